// Round 12
// baseline (575.278 us; speedup 1.0000x reference)
//
#include <hip/hip_runtime.h>
#include <hip/hip_bf16.h>

#define NN 100000
#define EE 500000
#define H 8
#define D 32
#define INF_ 32
#define HD 256
#define SLOPE 0.2f
#define L_ (4 * NN)
#define NB_ ((L_ + 255) / 256)

typedef unsigned short u16;
typedef unsigned int u32;
typedef short bf16x8 __attribute__((ext_vector_type(8)));
typedef float f32x4 __attribute__((ext_vector_type(4)));

union U8 { uint4 u; bf16x8 v; };

__device__ __forceinline__ float leaky(float x) { return x >= 0.f ? x : SLOPE * x; }
__device__ __forceinline__ u16 bf16r(float x) {
    u32 u = __float_as_uint(x);
    u += 0x7fffu + ((u >> 16) & 1u);
    return (u16)(u >> 16);
}
__device__ __forceinline__ float bf16f(u16 v) { return __uint_as_float((u32)v << 16); }
__device__ __forceinline__ u32 cvtpk(float lo, float hi) {
    u32 r;
    asm("v_cvt_pk_bf16_f32 %0, %1, %2" : "=v"(r) : "v"(lo), "v"(hi));
    return r;
}

// ---------------- tiny prep: ra[4][512] and rel_out[4][256] ----------------
__global__ void k_prep(const float* __restrict__ rel_emb, const float* __restrict__ W_rel,
                       const float* __restrict__ W_prop, const float* __restrict__ b_prop,
                       float* __restrict__ ra, float* __restrict__ rel_out) {
    int idx = blockIdx.x * blockDim.x + threadIdx.x;
    if (idx < 4 * 512) {
        int r = idx >> 9, o = idx & 511;
        float s = 0.f;
        #pragma unroll
        for (int i = 0; i < INF_; ++i) s += rel_emb[r * INF_ + i] * W_rel[(r * INF_ + i) * 512 + o];
        ra[idx] = s;
    } else if (idx < 4 * 512 + 4 * 256) {
        int j = idx - 2048;
        int r = j >> 8;
        float s = b_prop[j];
        #pragma unroll
        for (int i = 0; i < INF_; ++i) s += rel_emb[r * INF_ + i] * W_prop[(r * INF_ + i) * 256 + (j & 255)];
        rel_out[j] = s;
    }
}

// ---------------- build MFMA A-operand fragments (bf16) ----------------
__global__ void k_wfrag(const float* __restrict__ W_node, const float* __restrict__ W_res,
                        const float* __restrict__ ra, u16* __restrict__ Wfrag) {
    int idx = blockIdx.x * 256 + threadIdx.x;
    if (idx >= 68 * 512) return;
    int lb = idx & 511;
    int l = lb >> 3, b = lb & 7;
    int k = (l >> 4) * 8 + b, i = l & 15;
    float v;
    if (idx < 4 * 512) {
        int q = idx >> 9;
        int rq = q ^ 1;
        const float* W = W_node + (size_t)(q & 1) * 32 * 256;
        int h = i & 7;
        const float* rr = (i < 8) ? (ra + q * 512 + h * 64 + 32) : (ra + rq * 512 + h * 64);
        float s = 0.f;
        #pragma unroll
        for (int j = 0; j < 32; ++j) s += W[k * 256 + h * 32 + j] * rr[j];
        v = s;
    } else if (idx < 36 * 512) {
        int j = idx - 4 * 512;
        int ty = j >> 13;
        int ct = (j & 8191) >> 9;
        v = W_node[(size_t)ty * 32 * 256 + k * 256 + ct * 16 + i];
    } else {
        int j = idx - 36 * 512;
        int ty = j >> 13;
        int ct = (j & 8191) >> 9;
        v = W_res[(size_t)ty * 32 * 256 + k * 256 + ct * 16 + i];
    }
    Wfrag[idx] = bf16r(v);
}

// ---------------- scores + bf16 feat copy (1 MFMA per 16 nodes) ----------------
__global__ __launch_bounds__(256) void k_score(const float* __restrict__ feat,
                                               const u16* __restrict__ Wfrag,
                                               float* __restrict__ e_src,
                                               float* __restrict__ e_dst,
                                               u16* __restrict__ featb) {
    const int q = blockIdx.y, rq = q ^ 1;
    const int t = threadIdx.x, lane = t & 63;
    const int li = lane & 15, g = lane >> 4;
    const int wid = blockIdx.x * 4 + (t >> 6);
    const int nw = gridDim.x * 4;
    f32x4 zz = {0.f, 0.f, 0.f, 0.f};
    U8 a;
    a.u = *(const uint4*)(Wfrag + ((size_t)q * 64 + lane) * 8);
    const float* F = feat + (size_t)rq * NN * INF_;
    u16* Fb = featb + (size_t)rq * NN * INF_;
    for (int tile = wid; tile < NN / 16; tile += nw) {
        const int node = tile * 16 + li;
        const float* fp = F + node * 32 + g * 8;
        float4 f0 = *(const float4*)fp;
        float4 f1 = *(const float4*)(fp + 4);
        U8 b;
        b.u.x = cvtpk(f0.x, f0.y); b.u.y = cvtpk(f0.z, f0.w);
        b.u.z = cvtpk(f1.x, f1.y); b.u.w = cvtpk(f1.z, f1.w);
        *(uint4*)(Fb + node * 32 + g * 8) = b.u;
        f32x4 sc = __builtin_amdgcn_mfma_f32_16x16x32_bf16(a.v, b.v, zz, 0, 0, 0);
        float* sp = (g < 2) ? (e_src + ((size_t)q * NN + node) * 8 + (g & 1) * 4)
                            : (e_dst + ((size_t)rq * NN + node) * 8 + (g & 1) * 4);
        *(float4*)sp = make_float4(sc[0], sc[1], sc[2], sc[3]);
    }
}

// ---------------- CSR build ----------------
__global__ void k_count(const int* __restrict__ dst, u32* __restrict__ deg) {
    int idx = blockIdx.x * blockDim.x + threadIdx.x;
    if (idx >= 4 * EE) return;
    int r = idx / EE;
    atomicAdd(&deg[r * NN + dst[idx]], 1u);
}

__global__ void k_scan1(const u32* __restrict__ deg, u32* __restrict__ incl, u32* __restrict__ bsum) {
    __shared__ u32 sm[256];
    const int t = threadIdx.x;
    int i = blockIdx.x * 256 + t;
    u32 v = (i < L_) ? deg[i] : 0u;
    sm[t] = v;
    __syncthreads();
    for (int ofs = 1; ofs < 256; ofs <<= 1) {
        u32 x = (t >= ofs) ? sm[t - ofs] : 0u;
        __syncthreads();
        sm[t] += x;
        __syncthreads();
    }
    if (i < L_) incl[i] = sm[t];
    if (t == 255) bsum[blockIdx.x] = sm[255];
}

__global__ void k_scan2(const u32* __restrict__ bsum, u32* __restrict__ bofs) {
    __shared__ u32 sm[256];
    __shared__ u32 runS;
    const int t = threadIdx.x;
    if (t == 0) runS = 0u;
    __syncthreads();
    for (int c = 0; c < NB_; c += 256) {
        u32 v = (c + t < NB_) ? bsum[c + t] : 0u;
        sm[t] = v;
        __syncthreads();
        for (int ofs = 1; ofs < 256; ofs <<= 1) {
            u32 x = (t >= ofs) ? sm[t - ofs] : 0u;
            __syncthreads();
            sm[t] += x;
            __syncthreads();
        }
        u32 excl = sm[t] - v;
        if (c + t < NB_) bofs[c + t] = runS + excl;
        __syncthreads();
        if (t == 255) runS += sm[255];
        __syncthreads();
    }
}

__global__ void k_scan3(const u32* __restrict__ deg, const u32* __restrict__ incl,
                        const u32* __restrict__ bofs, u32* __restrict__ offsets,
                        u32* __restrict__ cursor) {
    int i = blockIdx.x * 256 + threadIdx.x;
    if (i >= L_) return;
    u32 excl = incl[i] - deg[i] + bofs[i >> 8];
    offsets[i] = excl;
    cursor[i] = excl;
}

__global__ void k_fill(const int* __restrict__ src, const int* __restrict__ dst,
                       u32* __restrict__ cursor, int* __restrict__ esorted) {
    int idx = blockIdx.x * blockDim.x + threadIdx.x;
    if (idx >= 4 * EE) return;
    int r = idx / EE;
    u32 pos = atomicAdd(&cursor[r * NN + dst[idx]], 1u);
    esorted[pos] = src[idx];
}

// ---------------- W-wide unguarded edge batch (32-bit addressing) ----------------
template <int W>
__device__ __forceinline__ void procW(const int* __restrict__ ep,
                                      const float* __restrict__ esr,
                                      const u16* __restrict__ Fb,
                                      int h, int fq4, float ed,
                                      float& z, float& a0, float& a1, float& a2, float& a3) {
    int s[W];
    #pragma unroll
    for (int j = 0; j < W; ++j) s[j] = ep[j];
    float e[W];
    ushort4 f[W];
    #pragma unroll
    for (int j = 0; j < W; ++j) {
        e[j] = esr[s[j] * 8 + h];                              // 32-bit idx, saddr form
        f[j] = *(const ushort4*)(Fb + s[j] * 32 + fq4);        // 32-bit idx, saddr form
    }
    float w[W];
    #pragma unroll
    for (int j = 0; j < W; ++j) w[j] = __expf(leaky(e[j] + ed));
    #pragma unroll
    for (int j = 0; j < W; ++j) {
        z += w[j];
        a0 = fmaf(bf16f(f[j].x), w[j], a0);
        a1 = fmaf(bf16f(f[j].y), w[j], a1);
        a2 = fmaf(bf16f(f[j].z), w[j], a2);
        a3 = fmaf(bf16f(f[j].w), w[j], a3);
    }
}

// ---------------- fused: per-node aggregation (LDS) + finalize MFMA ----------------
// 512-thread block (8 waves) = one 16-node tile of type ty; phase 1: 32 (node,rel)
// units, 4 sequential per wave; phase 2: 1 head per wave reading LDS aggregates.
__global__ __launch_bounds__(512) void k_msg_final(const u32* __restrict__ offsets,
                                                   const u32* __restrict__ deg,
                                                   const int* __restrict__ esorted,
                                                   const float* __restrict__ e_src,
                                                   const float* __restrict__ e_dst,
                                                   const u16* __restrict__ featb,
                                                   const u16* __restrict__ Wfrag,
                                                   const float* __restrict__ b_res,
                                                   const float* __restrict__ alpha,
                                                   const float* __restrict__ Wx,
                                                   float* __restrict__ outp) {
    const int ty = blockIdx.y;
    const int rA = ty ? 0 : 1, rB = ty ? 2 : 3;
    const int t = threadIdx.x, lane = t & 63, w = t >> 6;
    const int tile = blockIdx.x;
    __shared__ uint4 lag[2][16][33];   // [rel slot][node][h*4+g], padded stride 33

    // ---- phase 1: aggregation, 4 (node,rel) units per wave ----
    {
        const int h = lane >> 3, fq4 = (lane & 7) * 4;
        #pragma unroll 1
        for (int uu = 0; uu < 4; ++uu) {
            const int unit = uu * 8 + w;
            const int rs = unit >> 4, nl = unit & 15;
            const int r = rs ? rB : rA;
            const int node = tile * 16 + nl;
            const int i = r * NN + node;
            const u32 off = offsets[i], dg = deg[i];
            uint2 st = {0u, 0u};
            if (dg) {
                const float ed = e_dst[i * 8 + h];
                const float* esr = e_src + (size_t)r * NN * 8;
                const u16* Fb = featb + (size_t)(r ^ 1) * NN * INF_;
                const int* ep = esorted + off;
                float z = 0.f, a0 = 0.f, a1 = 0.f, a2 = 0.f, a3 = 0.f;
                u32 k = 0;
                for (; k + 8 <= dg; k += 8)
                    procW<8>(ep + k, esr, Fb, h, fq4, ed, z, a0, a1, a2, a3);
                u32 rem = dg - k;
                if (rem & 4) { procW<4>(ep + k, esr, Fb, h, fq4, ed, z, a0, a1, a2, a3); k += 4; }
                if (rem & 2) { procW<2>(ep + k, esr, Fb, h, fq4, ed, z, a0, a1, a2, a3); k += 2; }
                if (rem & 1) { procW<1>(ep + k, esr, Fb, h, fq4, ed, z, a0, a1, a2, a3); }
                float inv = 1.f / z;
                st.x = cvtpk(a0 * inv, a1 * inv);
                st.y = cvtpk(a2 * inv, a3 * inv);
            }
            *((uint2*)lag[rs][nl] + h * 8 + (fq4 >> 2)) = st;   // byte h*64 + fq*8
        }
    }
    __syncthreads();

    // ---- phase 2: finalize, 1 head per wave ----
    const int li = lane & 15, g = lane >> 4;
    const int node = tile * 16 + li;
    const int h = w;
    const float ga = 1.f / (1.f + __expf(-alpha[ty]));
    const float gb = 1.f - ga;
    f32x4 zz = {0.f, 0.f, 0.f, 0.f};
    const u16* WnF = Wfrag + (size_t)(4 + (1 - ty) * 16) * 512;   // W_node[st=1-ty]
    const u16* WrF = Wfrag + (size_t)(36 + ty * 16) * 512;        // W_res[dt=ty]
    const u16* FbA = featb + (size_t)rA * NN * INF_;
    const u16* FbB = featb + (size_t)rB * NN * INF_;

    U8 fA, fB;
    fA.u = *(const uint4*)(FbA + node * 32 + g * 8);
    fB.u = *(const uint4*)(FbB + node * 32 + g * 8);
    float* op = outp + (size_t)(ty * NN + node) * HD;

    U8 ag1, ag2;
    ag1.u = lag[0][li][h * 4 + g];
    ag2.u = lag[1][li][h * 4 + g];
    float o1[8], o2[8];
    float s1 = 0.f, s2 = 0.f;
    #pragma unroll
    for (int c2 = 0; c2 < 2; ++c2) {
        const int ct = h * 2 + c2;
        U8 wn, wr;
        wn.u = *(const uint4*)(WnF + ((size_t)ct * 64 + lane) * 8);
        wr.u = *(const uint4*)(WrF + ((size_t)ct * 64 + lane) * 8);
        f32x4 m1 = __builtin_amdgcn_mfma_f32_16x16x32_bf16(wn.v, ag1.v, zz, 0, 0, 0);
        f32x4 m2 = __builtin_amdgcn_mfma_f32_16x16x32_bf16(wn.v, ag2.v, zz, 0, 0, 0);
        f32x4 r1 = __builtin_amdgcn_mfma_f32_16x16x32_bf16(wr.v, fA.v, zz, 0, 0, 0);
        f32x4 r2 = __builtin_amdgcn_mfma_f32_16x16x32_bf16(wr.v, fB.v, zz, 0, 0, 0);
        float4 bv = *(const float4*)(b_res + ty * 256 + ct * 16 + g * 4);
        float4 wv = *(const float4*)(Wx + ty * 256 + ct * 16 + g * 4);
        #pragma unroll
        for (int j = 0; j < 4; ++j) {
            float bj = (&bv.x)[j], wj = (&wv.x)[j];
            float v1 = fmaxf(m1[j], 0.f) * ga + (r1[j] + bj) * gb;
            float v2 = fmaxf(m2[j], 0.f) * ga + (r2[j] + bj) * gb;
            o1[c2 * 4 + j] = v1;
            o2[c2 * 4 + j] = v2;
            s1 += v1 * wj;
            s2 += v2 * wj;
        }
    }
    s1 += __shfl_xor(s1, 16, 64);
    s1 += __shfl_xor(s1, 32, 64);
    s2 += __shfl_xor(s2, 16, 64);
    s2 += __shfl_xor(s2, 32, 64);
    float a1l = leaky(s1), a2l = leaky(s2);
    float mx = fmaxf(a1l, a2l);
    float e1 = __expf(a1l - mx), e2 = __expf(a2l - mx);
    float inv = 1.f / (e1 + e2);
    float wa = e1 * inv, wb = e2 * inv;
    #pragma unroll
    for (int c2 = 0; c2 < 2; ++c2) {
        const int ct = h * 2 + c2;
        float4 o;
        #pragma unroll
        for (int j = 0; j < 4; ++j)
            (&o.x)[j] = o1[c2 * 4 + j] * wa + o2[c2 * 4 + j] * wb;
        *(float4*)(op + ct * 16 + g * 4) = o;
    }
}

extern "C" void kernel_launch(void* const* d_in, const int* in_sizes, int n_in,
                              void* d_out, int out_size, void* d_ws, size_t ws_size,
                              hipStream_t stream) {
    const float* feat    = (const float*)d_in[0];
    const float* rel_emb = (const float*)d_in[1];
    const float* W_node  = (const float*)d_in[2];
    const float* W_rel   = (const float*)d_in[3];
    const float* W_prop  = (const float*)d_in[4];
    const float* b_prop  = (const float*)d_in[5];
    const float* W_res   = (const float*)d_in[6];
    const float* b_res   = (const float*)d_in[7];
    const float* alpha   = (const float*)d_in[8];
    const float* Wx      = (const float*)d_in[9];
    const int*   src     = (const int*)d_in[10];
    const int*   dst     = (const int*)d_in[11];
    float* out = (float*)d_out;

    // ws: ra | e_src | e_dst | featb | Wfrag | deg | offsets | cursor | incl | bsum | bofs | esorted
    char* ws = (char*)d_ws;
    float* ra      = (float*)ws;                            // 8 KB
    float* e_src   = (float*)(ws + 8192);                   // 12.8 MB
    float* e_dst   = e_src + (size_t)4 * NN * H;            // 12.8 MB
    u16*   featb   = (u16*)(e_dst + (size_t)4 * NN * H);    // 25.6 MB
    u16*   Wfrag   = featb + (size_t)4 * NN * INF_;         // 68 KB
    u32*   deg     = (u32*)(Wfrag + 68 * 512);
    u32*   offsets = deg + L_;
    u32*   cursor  = offsets + L_;
    u32*   incl    = cursor + L_;
    u32*   bsum    = incl + L_;
    u32*   bofs    = bsum + 2048;
    int*   esorted = (int*)(bofs + 2048);                   // 8 MB

    hipMemsetAsync(deg, 0, (size_t)L_ * 4, stream);

    k_prep<<<12, 256, 0, stream>>>(rel_emb, W_rel, W_prop, b_prop, ra, out + (size_t)2 * NN * HD);
    k_wfrag<<<136, 256, 0, stream>>>(W_node, W_res, ra, Wfrag);

    int eb = (4 * EE + 255) / 256;
    k_count<<<eb, 256, 0, stream>>>(dst, deg);
    k_scan1<<<NB_, 256, 0, stream>>>(deg, incl, bsum);
    k_scan2<<<1, 256, 0, stream>>>(bsum, bofs);
    k_scan3<<<NB_, 256, 0, stream>>>(deg, incl, bofs, offsets, cursor);
    k_fill<<<eb, 256, 0, stream>>>(src, dst, cursor, esorted);

    k_score<<<dim3(512, 4), 256, 0, stream>>>(feat, Wfrag, e_src, e_dst, featb);

    k_msg_final<<<dim3(NN / 16, 2), 512, 0, stream>>>(offsets, deg, esorted, e_src, e_dst,
                                                      featb, Wfrag, b_res, alpha, Wx, out);
}

// Round 13
// 444.501 us; speedup vs baseline: 1.2942x; 1.2942x over previous
//
#include <hip/hip_runtime.h>
#include <hip/hip_bf16.h>

#define NN 100000
#define EE 500000
#define H 8
#define D 32
#define INF_ 32
#define HD 256
#define SLOPE 0.2f
#define L_ (4 * NN)
#define NB_ ((L_ + 255) / 256)

typedef unsigned short u16;
typedef unsigned int u32;
typedef short bf16x8 __attribute__((ext_vector_type(8)));
typedef float f32x4 __attribute__((ext_vector_type(4)));

union U8 { uint4 u; bf16x8 v; };

__device__ __forceinline__ float leaky(float x) { return x >= 0.f ? x : SLOPE * x; }
__device__ __forceinline__ u16 bf16r(float x) {
    u32 u = __float_as_uint(x);
    u += 0x7fffu + ((u >> 16) & 1u);
    return (u16)(u >> 16);
}
__device__ __forceinline__ float bf16f(u16 v) { return __uint_as_float((u32)v << 16); }
__device__ __forceinline__ u32 cvtpk(float lo, float hi) {
    u32 r;
    asm("v_cvt_pk_bf16_f32 %0, %1, %2" : "=v"(r) : "v"(lo), "v"(hi));
    return r;
}

// ---------------- tiny prep: ra[4][512] and rel_out[4][256] ----------------
__global__ void k_prep(const float* __restrict__ rel_emb, const float* __restrict__ W_rel,
                       const float* __restrict__ W_prop, const float* __restrict__ b_prop,
                       float* __restrict__ ra, float* __restrict__ rel_out) {
    int idx = blockIdx.x * blockDim.x + threadIdx.x;
    if (idx < 4 * 512) {
        int r = idx >> 9, o = idx & 511;
        float s = 0.f;
        #pragma unroll
        for (int i = 0; i < INF_; ++i) s += rel_emb[r * INF_ + i] * W_rel[(r * INF_ + i) * 512 + o];
        ra[idx] = s;
    } else if (idx < 4 * 512 + 4 * 256) {
        int j = idx - 2048;
        int r = j >> 8;
        float s = b_prop[j];
        #pragma unroll
        for (int i = 0; i < INF_; ++i) s += rel_emb[r * INF_ + i] * W_prop[(r * INF_ + i) * 256 + (j & 255)];
        rel_out[j] = s;
    }
}

// ---------------- build MFMA A-operand fragments (bf16) ----------------
__global__ void k_wfrag(const float* __restrict__ W_node, const float* __restrict__ W_res,
                        const float* __restrict__ ra, u16* __restrict__ Wfrag) {
    int idx = blockIdx.x * 256 + threadIdx.x;
    if (idx >= 68 * 512) return;
    int lb = idx & 511;
    int l = lb >> 3, b = lb & 7;
    int k = (l >> 4) * 8 + b, i = l & 15;
    float v;
    if (idx < 4 * 512) {
        int q = idx >> 9;
        int rq = q ^ 1;
        const float* W = W_node + (size_t)(q & 1) * 32 * 256;
        int h = i & 7;
        const float* rr = (i < 8) ? (ra + q * 512 + h * 64 + 32) : (ra + rq * 512 + h * 64);
        float s = 0.f;
        #pragma unroll
        for (int j = 0; j < 32; ++j) s += W[k * 256 + h * 32 + j] * rr[j];
        v = s;
    } else if (idx < 36 * 512) {
        int j = idx - 4 * 512;
        int ty = j >> 13;
        int ct = (j & 8191) >> 9;
        v = W_node[(size_t)ty * 32 * 256 + k * 256 + ct * 16 + i];
    } else {
        int j = idx - 36 * 512;
        int ty = j >> 13;
        int ct = (j & 8191) >> 9;
        v = W_res[(size_t)ty * 32 * 256 + k * 256 + ct * 16 + i];
    }
    Wfrag[idx] = bf16r(v);
}

// ---------------- scores + bf16 feat copy (1 MFMA per 16 nodes) ----------------
__global__ __launch_bounds__(256) void k_score(const float* __restrict__ feat,
                                               const u16* __restrict__ Wfrag,
                                               float* __restrict__ e_src,
                                               float* __restrict__ e_dst,
                                               u16* __restrict__ featb) {
    const int q = blockIdx.y, rq = q ^ 1;
    const int t = threadIdx.x, lane = t & 63;
    const int li = lane & 15, g = lane >> 4;
    const int wid = blockIdx.x * 4 + (t >> 6);
    const int nw = gridDim.x * 4;
    f32x4 zz = {0.f, 0.f, 0.f, 0.f};
    U8 a;
    a.u = *(const uint4*)(Wfrag + ((size_t)q * 64 + lane) * 8);
    const float* F = feat + (size_t)rq * NN * INF_;
    u16* Fb = featb + (size_t)rq * NN * INF_;
    for (int tile = wid; tile < NN / 16; tile += nw) {
        const int node = tile * 16 + li;
        const float* fp = F + node * 32 + g * 8;
        float4 f0 = *(const float4*)fp;
        float4 f1 = *(const float4*)(fp + 4);
        U8 b;
        b.u.x = cvtpk(f0.x, f0.y); b.u.y = cvtpk(f0.z, f0.w);
        b.u.z = cvtpk(f1.x, f1.y); b.u.w = cvtpk(f1.z, f1.w);
        *(uint4*)(Fb + node * 32 + g * 8) = b.u;
        f32x4 sc = __builtin_amdgcn_mfma_f32_16x16x32_bf16(a.v, b.v, zz, 0, 0, 0);
        float* sp = (g < 2) ? (e_src + ((size_t)q * NN + node) * 8 + (g & 1) * 4)
                            : (e_dst + ((size_t)rq * NN + node) * 8 + (g & 1) * 4);
        *(float4*)sp = make_float4(sc[0], sc[1], sc[2], sc[3]);
    }
}

// ---------------- CSR build ----------------
// k_count also records each edge's rank within its dst segment -> k_fill is atomic-free.
__global__ void k_count(const int* __restrict__ dst, u32* __restrict__ deg, u32* __restrict__ epos) {
    int idx = blockIdx.x * blockDim.x + threadIdx.x;
    if (idx >= 4 * EE) return;
    int r = idx / EE;
    epos[idx] = atomicAdd(&deg[r * NN + dst[idx]], 1u);
}

__global__ void k_scan1(const u32* __restrict__ deg, u32* __restrict__ incl, u32* __restrict__ bsum) {
    __shared__ u32 sm[256];
    const int t = threadIdx.x;
    int i = blockIdx.x * 256 + t;
    u32 v = (i < L_) ? deg[i] : 0u;
    sm[t] = v;
    __syncthreads();
    for (int ofs = 1; ofs < 256; ofs <<= 1) {
        u32 x = (t >= ofs) ? sm[t - ofs] : 0u;
        __syncthreads();
        sm[t] += x;
        __syncthreads();
    }
    if (i < L_) incl[i] = sm[t];
    if (t == 255) bsum[blockIdx.x] = sm[255];
}

__global__ void k_scan2(const u32* __restrict__ bsum, u32* __restrict__ bofs) {
    __shared__ u32 sm[256];
    __shared__ u32 runS;
    const int t = threadIdx.x;
    if (t == 0) runS = 0u;
    __syncthreads();
    for (int c = 0; c < NB_; c += 256) {
        u32 v = (c + t < NB_) ? bsum[c + t] : 0u;
        sm[t] = v;
        __syncthreads();
        for (int ofs = 1; ofs < 256; ofs <<= 1) {
            u32 x = (t >= ofs) ? sm[t - ofs] : 0u;
            __syncthreads();
            sm[t] += x;
            __syncthreads();
        }
        u32 excl = sm[t] - v;
        if (c + t < NB_) bofs[c + t] = runS + excl;
        __syncthreads();
        if (t == 255) runS += sm[255];
        __syncthreads();
    }
}

__global__ void k_scan3(const u32* __restrict__ deg, const u32* __restrict__ incl,
                        const u32* __restrict__ bofs, u32* __restrict__ offsets) {
    int i = blockIdx.x * 256 + threadIdx.x;
    if (i >= L_) return;
    offsets[i] = incl[i] - deg[i] + bofs[i >> 8];
}

__global__ void k_fill(const int* __restrict__ src, const int* __restrict__ dst,
                       const u32* __restrict__ offsets, const u32* __restrict__ epos,
                       int* __restrict__ esorted) {
    int idx = blockIdx.x * blockDim.x + threadIdx.x;
    if (idx >= 4 * EE) return;
    int r = idx / EE;
    esorted[offsets[r * NN + dst[idx]] + epos[idx]] = src[idx];
}

// ---------------- W-wide unguarded edge batch ----------------
template <int W>
__device__ __forceinline__ void procW(const int* __restrict__ ep,
                                      const float* __restrict__ esr,
                                      const u16* __restrict__ Fb,
                                      int h, int fq, float ed,
                                      float& z, float& a0, float& a1, float& a2, float& a3) {
    int s[W];
    #pragma unroll
    for (int j = 0; j < W; ++j) s[j] = ep[j];
    float e[W];
    ushort4 f[W];
    #pragma unroll
    for (int j = 0; j < W; ++j) {
        e[j] = esr[(size_t)s[j] * 8 + h];
        f[j] = *(const ushort4*)(Fb + (size_t)s[j] * INF_ + fq * 4);
    }
    float w[W];
    #pragma unroll
    for (int j = 0; j < W; ++j) w[j] = __expf(leaky(e[j] + ed));
    #pragma unroll
    for (int j = 0; j < W; ++j) {
        z += w[j];
        a0 = fmaf(bf16f(f[j].x), w[j], a0);
        a1 = fmaf(bf16f(f[j].y), w[j], a1);
        a2 = fmaf(bf16f(f[j].z), w[j], a2);
        a3 = fmaf(bf16f(f[j].w), w[j], a3);
    }
}

// ---------------- fused: per-node aggregation (LDS) + finalize MFMA ----------------
// block = one 16-node tile of type ty; 2 relations (rA,rB) aggregated into LDS
// (32 units, 8 per wave), then finalize MFMA reads LDS. (R11 configuration.)
__global__ __launch_bounds__(256) void k_msg_final(const u32* __restrict__ offsets,
                                                   const u32* __restrict__ deg,
                                                   const int* __restrict__ esorted,
                                                   const float* __restrict__ e_src,
                                                   const float* __restrict__ e_dst,
                                                   const u16* __restrict__ featb,
                                                   const u16* __restrict__ Wfrag,
                                                   const float* __restrict__ b_res,
                                                   const float* __restrict__ alpha,
                                                   const float* __restrict__ Wx,
                                                   float* __restrict__ outp) {
    const int ty = blockIdx.y;
    const int rA = ty ? 0 : 1, rB = ty ? 2 : 3;
    const int t = threadIdx.x, lane = t & 63, w = t >> 6;
    const int tile = blockIdx.x;
    __shared__ uint4 lag[2][16][33];   // [rel slot][node][h*4+g], padded stride 33

    // ---- phase 1: aggregation, 8 (node,rel) units per wave ----
    {
        const int h = lane >> 3, fq = lane & 7;
        #pragma unroll 1
        for (int uu = 0; uu < 8; ++uu) {
            const int unit = uu * 4 + w;
            const int rs = unit >> 4, nl = unit & 15;
            const int r = rs ? rB : rA;
            const int node = tile * 16 + nl;
            const int i = r * NN + node;
            const u32 off = offsets[i], dg = deg[i];
            uint2 st = {0u, 0u};
            if (dg) {
                const float ed = e_dst[(size_t)i * 8 + h];
                const float* esr = e_src + (size_t)r * NN * 8;
                const u16* Fb = featb + (size_t)(r ^ 1) * NN * INF_;
                const int* ep = esorted + off;
                float z = 0.f, a0 = 0.f, a1 = 0.f, a2 = 0.f, a3 = 0.f;
                u32 k = 0;
                for (; k + 8 <= dg; k += 8)
                    procW<8>(ep + k, esr, Fb, h, fq, ed, z, a0, a1, a2, a3);
                u32 rem = dg - k;
                if (rem & 4) { procW<4>(ep + k, esr, Fb, h, fq, ed, z, a0, a1, a2, a3); k += 4; }
                if (rem & 2) { procW<2>(ep + k, esr, Fb, h, fq, ed, z, a0, a1, a2, a3); k += 2; }
                if (rem & 1) { procW<1>(ep + k, esr, Fb, h, fq, ed, z, a0, a1, a2, a3); }
                float inv = 1.f / z;
                st.x = cvtpk(a0 * inv, a1 * inv);
                st.y = cvtpk(a2 * inv, a3 * inv);
            }
            *((uint2*)lag[rs][nl] + h * 8 + fq) = st;   // byte h*64 + fq*8
        }
    }
    __syncthreads();

    // ---- phase 2: finalize (heads split across waves) ----
    const int li = lane & 15, g = lane >> 4;
    const int node = tile * 16 + li;
    const float ga = 1.f / (1.f + __expf(-alpha[ty]));
    const float gb = 1.f - ga;
    f32x4 zz = {0.f, 0.f, 0.f, 0.f};
    const u16* WnF = Wfrag + (size_t)(4 + (1 - ty) * 16) * 512;   // W_node[st=1-ty]
    const u16* WrF = Wfrag + (size_t)(36 + ty * 16) * 512;        // W_res[dt=ty]
    const u16* FbA = featb + (size_t)rA * NN * INF_;
    const u16* FbB = featb + (size_t)rB * NN * INF_;

    U8 fA, fB;
    fA.u = *(const uint4*)(FbA + (size_t)node * 32 + g * 8);
    fB.u = *(const uint4*)(FbB + (size_t)node * 32 + g * 8);
    float* op = outp + ((size_t)ty * NN + node) * HD;

    #pragma unroll
    for (int hh = 0; hh < 2; ++hh) {
        const int h = w + hh * 4;
        U8 ag1, ag2;
        ag1.u = lag[0][li][h * 4 + g];
        ag2.u = lag[1][li][h * 4 + g];
        float o1[8], o2[8];
        float s1 = 0.f, s2 = 0.f;
        #pragma unroll
        for (int c2 = 0; c2 < 2; ++c2) {
            const int ct = h * 2 + c2;
            U8 wn, wr;
            wn.u = *(const uint4*)(WnF + ((size_t)ct * 64 + lane) * 8);
            wr.u = *(const uint4*)(WrF + ((size_t)ct * 64 + lane) * 8);
            f32x4 m1 = __builtin_amdgcn_mfma_f32_16x16x32_bf16(wn.v, ag1.v, zz, 0, 0, 0);
            f32x4 m2 = __builtin_amdgcn_mfma_f32_16x16x32_bf16(wn.v, ag2.v, zz, 0, 0, 0);
            f32x4 r1 = __builtin_amdgcn_mfma_f32_16x16x32_bf16(wr.v, fA.v, zz, 0, 0, 0);
            f32x4 r2 = __builtin_amdgcn_mfma_f32_16x16x32_bf16(wr.v, fB.v, zz, 0, 0, 0);
            float4 bv = *(const float4*)(b_res + ty * 256 + ct * 16 + g * 4);
            float4 wv = *(const float4*)(Wx + ty * 256 + ct * 16 + g * 4);
            #pragma unroll
            for (int j = 0; j < 4; ++j) {
                float bj = (&bv.x)[j], wj = (&wv.x)[j];
                float v1 = fmaxf(m1[j], 0.f) * ga + (r1[j] + bj) * gb;
                float v2 = fmaxf(m2[j], 0.f) * ga + (r2[j] + bj) * gb;
                o1[c2 * 4 + j] = v1;
                o2[c2 * 4 + j] = v2;
                s1 += v1 * wj;
                s2 += v2 * wj;
            }
        }
        s1 += __shfl_xor(s1, 16, 64);
        s1 += __shfl_xor(s1, 32, 64);
        s2 += __shfl_xor(s2, 16, 64);
        s2 += __shfl_xor(s2, 32, 64);
        float a1l = leaky(s1), a2l = leaky(s2);
        float mx = fmaxf(a1l, a2l);
        float e1 = __expf(a1l - mx), e2 = __expf(a2l - mx);
        float inv = 1.f / (e1 + e2);
        float wa = e1 * inv, wb = e2 * inv;
        #pragma unroll
        for (int c2 = 0; c2 < 2; ++c2) {
            const int ct = h * 2 + c2;
            float4 o;
            #pragma unroll
            for (int j = 0; j < 4; ++j)
                (&o.x)[j] = o1[c2 * 4 + j] * wa + o2[c2 * 4 + j] * wb;
            *(float4*)(op + ct * 16 + g * 4) = o;
        }
    }
}

extern "C" void kernel_launch(void* const* d_in, const int* in_sizes, int n_in,
                              void* d_out, int out_size, void* d_ws, size_t ws_size,
                              hipStream_t stream) {
    const float* feat    = (const float*)d_in[0];
    const float* rel_emb = (const float*)d_in[1];
    const float* W_node  = (const float*)d_in[2];
    const float* W_rel   = (const float*)d_in[3];
    const float* W_prop  = (const float*)d_in[4];
    const float* b_prop  = (const float*)d_in[5];
    const float* W_res   = (const float*)d_in[6];
    const float* b_res   = (const float*)d_in[7];
    const float* alpha   = (const float*)d_in[8];
    const float* Wx      = (const float*)d_in[9];
    const int*   src     = (const int*)d_in[10];
    const int*   dst     = (const int*)d_in[11];
    float* out = (float*)d_out;

    // ws: ra | e_src | e_dst | featb | Wfrag | deg | offsets | incl | bsum | bofs | epos | esorted
    char* ws = (char*)d_ws;
    float* ra      = (float*)ws;                            // 8 KB
    float* e_src   = (float*)(ws + 8192);                   // 12.8 MB
    float* e_dst   = e_src + (size_t)4 * NN * H;            // 12.8 MB
    u16*   featb   = (u16*)(e_dst + (size_t)4 * NN * H);    // 25.6 MB
    u16*   Wfrag   = featb + (size_t)4 * NN * INF_;         // 68 KB
    u32*   deg     = (u32*)(Wfrag + 68 * 512);
    u32*   offsets = deg + L_;
    u32*   incl    = offsets + L_;
    u32*   bsum    = incl + L_;
    u32*   bofs    = bsum + 2048;
    u32*   epos    = bofs + 2048;                           // 8 MB
    int*   esorted = (int*)(epos + (size_t)4 * EE);         // 8 MB

    hipMemsetAsync(deg, 0, (size_t)L_ * 4, stream);

    k_prep<<<12, 256, 0, stream>>>(rel_emb, W_rel, W_prop, b_prop, ra, out + (size_t)2 * NN * HD);
    k_wfrag<<<136, 256, 0, stream>>>(W_node, W_res, ra, Wfrag);

    int eb = (4 * EE + 255) / 256;
    k_count<<<eb, 256, 0, stream>>>(dst, deg, epos);
    k_scan1<<<NB_, 256, 0, stream>>>(deg, incl, bsum);
    k_scan2<<<1, 256, 0, stream>>>(bsum, bofs);
    k_scan3<<<NB_, 256, 0, stream>>>(deg, incl, bofs, offsets);
    k_fill<<<eb, 256, 0, stream>>>(src, dst, offsets, epos, esorted);

    k_score<<<dim3(512, 4), 256, 0, stream>>>(feat, Wfrag, e_src, e_dst, featb);

    k_msg_final<<<dim3(NN / 16, 2), 256, 0, stream>>>(offsets, deg, esorted, e_src, e_dst,
                                                      featb, Wfrag, b_res, alpha, Wx, out);
}

// Round 14
// 416.207 us; speedup vs baseline: 1.3822x; 1.0680x over previous
//
#include <hip/hip_runtime.h>
#include <hip/hip_bf16.h>

#define NN 100000
#define EE 500000
#define H 8
#define D 32
#define INF_ 32
#define HD 256
#define SLOPE 0.2f
#define L_ (4 * NN)
#define NB_ ((L_ + 255) / 256)

typedef unsigned short u16;
typedef unsigned int u32;
typedef short bf16x8 __attribute__((ext_vector_type(8)));
typedef float f32x4 __attribute__((ext_vector_type(4)));

union U8 { uint4 u; bf16x8 v; };

__device__ __forceinline__ float leaky(float x) { return x >= 0.f ? x : SLOPE * x; }
__device__ __forceinline__ u16 bf16r(float x) {
    u32 u = __float_as_uint(x);
    u += 0x7fffu + ((u >> 16) & 1u);
    return (u16)(u >> 16);
}
__device__ __forceinline__ float bf16f(u16 v) { return __uint_as_float((u32)v << 16); }
__device__ __forceinline__ u32 cvtpk(float lo, float hi) {
    u32 r;
    asm("v_cvt_pk_bf16_f32 %0, %1, %2" : "=v"(r) : "v"(lo), "v"(hi));
    return r;
}

// ---------------- tiny prep: ra[4][512] and rel_out[4][256] ----------------
__global__ void k_prep(const float* __restrict__ rel_emb, const float* __restrict__ W_rel,
                       const float* __restrict__ W_prop, const float* __restrict__ b_prop,
                       float* __restrict__ ra, float* __restrict__ rel_out) {
    int idx = blockIdx.x * blockDim.x + threadIdx.x;
    if (idx < 4 * 512) {
        int r = idx >> 9, o = idx & 511;
        float s = 0.f;
        #pragma unroll
        for (int i = 0; i < INF_; ++i) s += rel_emb[r * INF_ + i] * W_rel[(r * INF_ + i) * 512 + o];
        ra[idx] = s;
    } else if (idx < 4 * 512 + 4 * 256) {
        int j = idx - 2048;
        int r = j >> 8;
        float s = b_prop[j];
        #pragma unroll
        for (int i = 0; i < INF_; ++i) s += rel_emb[r * INF_ + i] * W_prop[(r * INF_ + i) * 256 + (j & 255)];
        rel_out[j] = s;
    }
}

// ---------------- build MFMA A-operand fragments (bf16) ----------------
__global__ void k_wfrag(const float* __restrict__ W_node, const float* __restrict__ W_res,
                        const float* __restrict__ ra, u16* __restrict__ Wfrag) {
    int idx = blockIdx.x * 256 + threadIdx.x;
    if (idx >= 68 * 512) return;
    int lb = idx & 511;
    int l = lb >> 3, b = lb & 7;
    int k = (l >> 4) * 8 + b, i = l & 15;
    float v;
    if (idx < 4 * 512) {
        int q = idx >> 9;
        int rq = q ^ 1;
        const float* W = W_node + (size_t)(q & 1) * 32 * 256;
        int h = i & 7;
        const float* rr = (i < 8) ? (ra + q * 512 + h * 64 + 32) : (ra + rq * 512 + h * 64);
        float s = 0.f;
        #pragma unroll
        for (int j = 0; j < 32; ++j) s += W[k * 256 + h * 32 + j] * rr[j];
        v = s;
    } else if (idx < 36 * 512) {
        int j = idx - 4 * 512;
        int ty = j >> 13;
        int ct = (j & 8191) >> 9;
        v = W_node[(size_t)ty * 32 * 256 + k * 256 + ct * 16 + i];
    } else {
        int j = idx - 36 * 512;
        int ty = j >> 13;
        int ct = (j & 8191) >> 9;
        v = W_res[(size_t)ty * 32 * 256 + k * 256 + ct * 16 + i];
    }
    Wfrag[idx] = bf16r(v);
}

// ---------------- scores + packed per-node record ----------------
// pk[q][n] (128 B): bytes 0-31  e_src[q][n]   (8 f32)
//                   bytes 32-95 feat[q^1][n]  (32 bf16)
//                   bytes 96-127 e_dst[q^1][n](8 f32)
// Every lane writes exactly two 16B chunks -> full-line coalesced.
__global__ __launch_bounds__(256) void k_score(const float* __restrict__ feat,
                                               const u16* __restrict__ Wfrag,
                                               char* __restrict__ pk) {
    const int q = blockIdx.y, rq = q ^ 1;
    const int t = threadIdx.x, lane = t & 63;
    const int li = lane & 15, g = lane >> 4;
    const int wid = blockIdx.x * 4 + (t >> 6);
    const int nw = gridDim.x * 4;
    f32x4 zz = {0.f, 0.f, 0.f, 0.f};
    U8 a;
    a.u = *(const uint4*)(Wfrag + ((size_t)q * 64 + lane) * 8);
    const float* F = feat + (size_t)rq * NN * INF_;
    char* pkq = pk + (size_t)q * NN * 128;
    for (int tile = wid; tile < NN / 16; tile += nw) {
        const int node = tile * 16 + li;
        const float* fp = F + node * 32 + g * 8;
        float4 f0 = *(const float4*)fp;
        float4 f1 = *(const float4*)(fp + 4);
        U8 b;
        b.u.x = cvtpk(f0.x, f0.y); b.u.y = cvtpk(f0.z, f0.w);
        b.u.z = cvtpk(f1.x, f1.y); b.u.w = cvtpk(f1.z, f1.w);
        char* rec = pkq + (size_t)node * 128;
        *(uint4*)(rec + 32 + g * 16) = b.u;
        f32x4 sc = __builtin_amdgcn_mfma_f32_16x16x32_bf16(a.v, b.v, zz, 0, 0, 0);
        char* sp = rec + ((g < 2) ? g * 16 : 96 + (g - 2) * 16);
        *(float4*)sp = make_float4(sc[0], sc[1], sc[2], sc[3]);
    }
}

// ---------------- CSR build (atomic-free fill via epos) ----------------
__global__ void k_count(const int* __restrict__ dst, u32* __restrict__ deg, u32* __restrict__ epos) {
    int idx = blockIdx.x * blockDim.x + threadIdx.x;
    if (idx >= 4 * EE) return;
    int r = idx / EE;
    epos[idx] = atomicAdd(&deg[r * NN + dst[idx]], 1u);
}

__global__ void k_scan1(const u32* __restrict__ deg, u32* __restrict__ incl, u32* __restrict__ bsum) {
    __shared__ u32 sm[256];
    const int t = threadIdx.x;
    int i = blockIdx.x * 256 + t;
    u32 v = (i < L_) ? deg[i] : 0u;
    sm[t] = v;
    __syncthreads();
    for (int ofs = 1; ofs < 256; ofs <<= 1) {
        u32 x = (t >= ofs) ? sm[t - ofs] : 0u;
        __syncthreads();
        sm[t] += x;
        __syncthreads();
    }
    if (i < L_) incl[i] = sm[t];
    if (t == 255) bsum[blockIdx.x] = sm[255];
}

__global__ void k_scan2(const u32* __restrict__ bsum, u32* __restrict__ bofs) {
    __shared__ u32 sm[256];
    __shared__ u32 runS;
    const int t = threadIdx.x;
    if (t == 0) runS = 0u;
    __syncthreads();
    for (int c = 0; c < NB_; c += 256) {
        u32 v = (c + t < NB_) ? bsum[c + t] : 0u;
        sm[t] = v;
        __syncthreads();
        for (int ofs = 1; ofs < 256; ofs <<= 1) {
            u32 x = (t >= ofs) ? sm[t - ofs] : 0u;
            __syncthreads();
            sm[t] += x;
            __syncthreads();
        }
        u32 excl = sm[t] - v;
        if (c + t < NB_) bofs[c + t] = runS + excl;
        __syncthreads();
        if (t == 255) runS += sm[255];
        __syncthreads();
    }
}

__global__ void k_scan3(const u32* __restrict__ deg, const u32* __restrict__ incl,
                        const u32* __restrict__ bofs, u32* __restrict__ offsets) {
    int i = blockIdx.x * 256 + threadIdx.x;
    if (i >= L_) return;
    offsets[i] = incl[i] - deg[i] + bofs[i >> 8];
}

__global__ void k_fill(const int* __restrict__ src, const int* __restrict__ dst,
                       const u32* __restrict__ offsets, const u32* __restrict__ epos,
                       int* __restrict__ esorted) {
    int idx = blockIdx.x * blockDim.x + threadIdx.x;
    if (idx >= 4 * EE) return;
    int r = idx / EE;
    esorted[offsets[r * NN + dst[idx]] + epos[idx]] = src[idx];
}

// ---------------- W-wide unguarded edge batch (packed-record gather) ----------------
template <int W>
__device__ __forceinline__ void procW(const int* __restrict__ ep,
                                      const char* __restrict__ pkr,
                                      int h, int fq, float ed,
                                      float& z, float& a0, float& a1, float& a2, float& a3) {
    int s[W];
    #pragma unroll
    for (int j = 0; j < W; ++j) s[j] = ep[j];
    float e[W];
    ushort4 f[W];
    #pragma unroll
    for (int j = 0; j < W; ++j) {
        const char* rec = pkr + (size_t)s[j] * 128;
        e[j] = *(const float*)(rec + h * 4);
        f[j] = *(const ushort4*)(rec + 32 + fq * 8);
    }
    float w[W];
    #pragma unroll
    for (int j = 0; j < W; ++j) w[j] = __expf(leaky(e[j] + ed));
    #pragma unroll
    for (int j = 0; j < W; ++j) {
        z += w[j];
        a0 = fmaf(bf16f(f[j].x), w[j], a0);
        a1 = fmaf(bf16f(f[j].y), w[j], a1);
        a2 = fmaf(bf16f(f[j].z), w[j], a2);
        a3 = fmaf(bf16f(f[j].w), w[j], a3);
    }
}

// ---------------- fused: per-node aggregation (LDS) + finalize MFMA ----------------
__global__ __launch_bounds__(256) void k_msg_final(const u32* __restrict__ offsets,
                                                   const u32* __restrict__ deg,
                                                   const int* __restrict__ esorted,
                                                   const char* __restrict__ pk,
                                                   const u16* __restrict__ Wfrag,
                                                   const float* __restrict__ b_res,
                                                   const float* __restrict__ alpha,
                                                   const float* __restrict__ Wx,
                                                   float* __restrict__ outp) {
    const int ty = blockIdx.y;
    const int rA = ty ? 0 : 1, rB = ty ? 2 : 3;
    const int t = threadIdx.x, lane = t & 63, w = t >> 6;
    const int tile = blockIdx.x;
    __shared__ uint4 lag[2][16][33];   // [rel slot][node][h*4+g], padded stride 33

    // shuffle-prefetch offsets/deg for all 32 units of this tile
    u32 odv;
    {
        int seg = lane >> 4, nl0 = lane & 15;
        int ii = ((seg < 2) ? rA : rB) * NN + tile * 16 + nl0;
        odv = (seg & 1) ? deg[ii] : offsets[ii];
    }

    // ---- phase 1: aggregation, 8 (node,rel) units per wave ----
    {
        const int h = lane >> 3, fq = lane & 7;
        #pragma unroll 1
        for (int uu = 0; uu < 8; ++uu) {
            const int unit = uu * 4 + w;
            const int rs = unit >> 4, nl = unit & 15;
            const int r = rs ? rB : rA;
            const int node = tile * 16 + nl;
            const u32 off = __shfl(odv, (rs << 5) + nl, 64);
            const u32 dg  = __shfl(odv, (rs << 5) + 16 + nl, 64);
            uint2 st = {0u, 0u};
            if (dg) {
                // e_dst[r][node] lives in pk[r^1][node] bytes 96-127
                const float ed = *(const float*)(pk + ((size_t)(r ^ 1) * NN + node) * 128 + 96 + h * 4);
                const char* pkr = pk + (size_t)r * NN * 128;
                const int* ep = esorted + off;
                float z = 0.f, a0 = 0.f, a1 = 0.f, a2 = 0.f, a3 = 0.f;
                u32 k = 0;
                for (; k + 8 <= dg; k += 8)
                    procW<8>(ep + k, pkr, h, fq, ed, z, a0, a1, a2, a3);
                u32 rem = dg - k;
                if (rem & 4) { procW<4>(ep + k, pkr, h, fq, ed, z, a0, a1, a2, a3); k += 4; }
                if (rem & 2) { procW<2>(ep + k, pkr, h, fq, ed, z, a0, a1, a2, a3); k += 2; }
                if (rem & 1) { procW<1>(ep + k, pkr, h, fq, ed, z, a0, a1, a2, a3); }
                float inv = 1.f / z;
                st.x = cvtpk(a0 * inv, a1 * inv);
                st.y = cvtpk(a2 * inv, a3 * inv);
            }
            *((uint2*)lag[rs][nl] + h * 8 + fq) = st;   // byte h*64 + fq*8
        }
    }
    __syncthreads();

    // ---- phase 2: finalize (heads split across waves) ----
    const int li = lane & 15, g = lane >> 4;
    const int node = tile * 16 + li;
    const float ga = 1.f / (1.f + __expf(-alpha[ty]));
    const float gb = 1.f - ga;
    f32x4 zz = {0.f, 0.f, 0.f, 0.f};
    const u16* WnF = Wfrag + (size_t)(4 + (1 - ty) * 16) * 512;   // W_node[st=1-ty]
    const u16* WrF = Wfrag + (size_t)(36 + ty * 16) * 512;        // W_res[dt=ty]

    U8 fA, fB;   // feat[rA] lives in pk[rA^1] bytes 32-95; feat[rB] in pk[rB^1]
    fA.u = *(const uint4*)(pk + ((size_t)(rA ^ 1) * NN + node) * 128 + 32 + g * 16);
    fB.u = *(const uint4*)(pk + ((size_t)(rB ^ 1) * NN + node) * 128 + 32 + g * 16);
    float* op = outp + ((size_t)ty * NN + node) * HD;

    #pragma unroll
    for (int hh = 0; hh < 2; ++hh) {
        const int h = w + hh * 4;
        U8 ag1, ag2;
        ag1.u = lag[0][li][h * 4 + g];
        ag2.u = lag[1][li][h * 4 + g];
        float o1[8], o2[8];
        float s1 = 0.f, s2 = 0.f;
        #pragma unroll
        for (int c2 = 0; c2 < 2; ++c2) {
            const int ct = h * 2 + c2;
            U8 wn, wr;
            wn.u = *(const uint4*)(WnF + ((size_t)ct * 64 + lane) * 8);
            wr.u = *(const uint4*)(WrF + ((size_t)ct * 64 + lane) * 8);
            f32x4 m1 = __builtin_amdgcn_mfma_f32_16x16x32_bf16(wn.v, ag1.v, zz, 0, 0, 0);
            f32x4 m2 = __builtin_amdgcn_mfma_f32_16x16x32_bf16(wn.v, ag2.v, zz, 0, 0, 0);
            f32x4 r1 = __builtin_amdgcn_mfma_f32_16x16x32_bf16(wr.v, fA.v, zz, 0, 0, 0);
            f32x4 r2 = __builtin_amdgcn_mfma_f32_16x16x32_bf16(wr.v, fB.v, zz, 0, 0, 0);
            float4 bv = *(const float4*)(b_res + ty * 256 + ct * 16 + g * 4);
            float4 wv = *(const float4*)(Wx + ty * 256 + ct * 16 + g * 4);
            #pragma unroll
            for (int j = 0; j < 4; ++j) {
                float bj = (&bv.x)[j], wj = (&wv.x)[j];
                float v1 = fmaxf(m1[j], 0.f) * ga + (r1[j] + bj) * gb;
                float v2 = fmaxf(m2[j], 0.f) * ga + (r2[j] + bj) * gb;
                o1[c2 * 4 + j] = v1;
                o2[c2 * 4 + j] = v2;
                s1 += v1 * wj;
                s2 += v2 * wj;
            }
        }
        s1 += __shfl_xor(s1, 16, 64);
        s1 += __shfl_xor(s1, 32, 64);
        s2 += __shfl_xor(s2, 16, 64);
        s2 += __shfl_xor(s2, 32, 64);
        float a1l = leaky(s1), a2l = leaky(s2);
        float mx = fmaxf(a1l, a2l);
        float e1 = __expf(a1l - mx), e2 = __expf(a2l - mx);
        float inv = 1.f / (e1 + e2);
        float wa = e1 * inv, wb = e2 * inv;
        #pragma unroll
        for (int c2 = 0; c2 < 2; ++c2) {
            const int ct = h * 2 + c2;
            float4 o;
            #pragma unroll
            for (int j = 0; j < 4; ++j)
                (&o.x)[j] = o1[c2 * 4 + j] * wa + o2[c2 * 4 + j] * wb;
            *(float4*)(op + ct * 16 + g * 4) = o;
        }
    }
}

extern "C" void kernel_launch(void* const* d_in, const int* in_sizes, int n_in,
                              void* d_out, int out_size, void* d_ws, size_t ws_size,
                              hipStream_t stream) {
    const float* feat    = (const float*)d_in[0];
    const float* rel_emb = (const float*)d_in[1];
    const float* W_node  = (const float*)d_in[2];
    const float* W_rel   = (const float*)d_in[3];
    const float* W_prop  = (const float*)d_in[4];
    const float* b_prop  = (const float*)d_in[5];
    const float* W_res   = (const float*)d_in[6];
    const float* b_res   = (const float*)d_in[7];
    const float* alpha   = (const float*)d_in[8];
    const float* Wx      = (const float*)d_in[9];
    const int*   src     = (const int*)d_in[10];
    const int*   dst     = (const int*)d_in[11];
    float* out = (float*)d_out;

    // ws: ra | pk(51.2MB,128-aligned) | Wfrag | deg | offsets | incl | bsum | bofs | epos | esorted
    char* ws = (char*)d_ws;
    float* ra      = (float*)ws;                            // 8 KB
    char*  pk      = ws + 8192;                             // 4*NN*128 = 51.2 MB
    u16*   Wfrag   = (u16*)(pk + (size_t)4 * NN * 128);     // 68 KB
    u32*   deg     = (u32*)((char*)Wfrag + 68 * 512 * 2);
    u32*   offsets = deg + L_;
    u32*   incl    = offsets + L_;
    u32*   bsum    = incl + L_;
    u32*   bofs    = bsum + 2048;
    u32*   epos    = bofs + 2048;                           // 8 MB
    int*   esorted = (int*)(epos + (size_t)4 * EE);         // 8 MB

    hipMemsetAsync(deg, 0, (size_t)L_ * 4, stream);

    k_prep<<<12, 256, 0, stream>>>(rel_emb, W_rel, W_prop, b_prop, ra, out + (size_t)2 * NN * HD);
    k_wfrag<<<136, 256, 0, stream>>>(W_node, W_res, ra, Wfrag);

    int eb = (4 * EE + 255) / 256;
    k_count<<<eb, 256, 0, stream>>>(dst, deg, epos);
    k_scan1<<<NB_, 256, 0, stream>>>(deg, incl, bsum);
    k_scan2<<<1, 256, 0, stream>>>(bsum, bofs);
    k_scan3<<<NB_, 256, 0, stream>>>(deg, incl, bofs, offsets);
    k_fill<<<eb, 256, 0, stream>>>(src, dst, offsets, epos, esorted);

    k_score<<<dim3(512, 4), 256, 0, stream>>>(feat, Wfrag, pk);

    k_msg_final<<<dim3(NN / 16, 2), 256, 0, stream>>>(offsets, deg, esorted, pk,
                                                      Wfrag, b_res, alpha, Wx, out);
}